// Round 1
// baseline (683.716 us; speedup 1.0000x reference)
//
#include <hip/hip_runtime.h>
#include <stdint.h>

typedef _Float16 half8 __attribute__((ext_vector_type(8)));
typedef float floatx4 __attribute__((ext_vector_type(4)));

constexpr int T  = 4096;
constexpr int KD = 64;    // known dim
constexpr int HD = 128;   // hidden dim
constexpr int BD = 128;   // batch
constexpr int KT = KD + HD;   // 192 = combined W rows / B-vector length
constexpr int CH = 64;        // chunks
constexpr int LS = T / CH;    // 64 steps per chunk
constexpr int BC = 32;        // batch cols per block
constexpr int NSP = BD / BC;  // 4 batch splits

static_assert(CH * LS == T, "");

// ws layout
constexpr size_t W_OFF = 0;                              // 192*192 f16 = 73728 B
constexpr size_t M_OFF = 73728;                          // 128*128 f16 = 32768 B
constexpr size_t U_OFF = 131072;                         // CH*HD*BD fp32 = 4 MB
constexpr size_t S_OFF = U_OFF + (size_t)CH * HD * BD * 4;

__device__ __forceinline__ unsigned short f2h(float v) {
  _Float16 h = (_Float16)v;
  return __builtin_bit_cast(unsigned short, h);
}
__device__ __forceinline__ unsigned pack2(float a, float b) {
  return (unsigned)f2h(a) | ((unsigned)f2h(b) << 16);
}
// XOR swizzle of 16B groups within aligned 8-group sets: conflict-free b128 reads
__device__ __forceinline__ int swz(int g, int n) {
  return (g & ~7) | ((g & 7) ^ (n & 7));
}

// ---------------------------------------------------------------------------
// prep: build W (f16, row-major [192][192]) and M = A4^64 (f16 [128][128])
// ---------------------------------------------------------------------------
__global__ __launch_bounds__(256) void prep_kernel(
    const float* __restrict__ A1, const float* __restrict__ A2,
    const float* __restrict__ A3, const float* __restrict__ A4,
    unsigned short* __restrict__ Wf, unsigned short* __restrict__ Mf) {
  if (blockIdx.x < 36) {
    for (int e = 0; e < 4; ++e) {
      int id = blockIdx.x * 1024 + e * 256 + threadIdx.x;  // 36*1024 = 36864 = 192*192
      int r = id / KT, cc = id % KT;
      float v;
      if (r < KD) v = (cc < KD) ? A1[r * KD + cc] : A2[r * HD + (cc - KD)];
      else        v = (cc < KD) ? A3[(r - KD) * KD + cc] : A4[(r - KD) * HD + (cc - KD)];
      Wf[id] = f2h(v);
    }
    return;
  }
  // block 36: M = A4^64 via 6 in-LDS squarings (Mrow row-major, Mcol transposed)
  __shared__ __align__(16) unsigned short Mrow[HD * HD];
  __shared__ __align__(16) unsigned short Mcol[HD * HD];
  const int tid = threadIdx.x;
  for (int j = 0; j < 64; ++j) {
    int id = j * 256 + tid;
    int r = id >> 7, cc = id & 127;
    unsigned short hb = f2h(A4[id]);
    Mrow[id] = hb;
    Mcol[cc * HD + r] = hb;
  }
  __syncthreads();
  const int wv = tid >> 6, ln = tid & 63, l15 = ln & 15, q = ln >> 4;
  for (int it = 0; it < 6; ++it) {
    half8 af[2][4];
#pragma unroll
    for (int m = 0; m < 2; ++m)
#pragma unroll
      for (int kt = 0; kt < 4; ++kt)
        af[m][kt] = *reinterpret_cast<const half8*>(
            &Mrow[(wv * 32 + m * 16 + l15) * HD + kt * 32 + q * 8]);
    floatx4 acc[2][8];
#pragma unroll
    for (int m = 0; m < 2; ++m)
#pragma unroll
      for (int nt = 0; nt < 8; ++nt) {
        floatx4 z = {0.f, 0.f, 0.f, 0.f};
        acc[m][nt] = z;
      }
#pragma unroll
    for (int kt = 0; kt < 4; ++kt)
#pragma unroll
      for (int nt = 0; nt < 8; ++nt) {
        half8 bf = *reinterpret_cast<const half8*>(
            &Mcol[(nt * 16 + l15) * HD + kt * 32 + q * 8]);
#pragma unroll
        for (int m = 0; m < 2; ++m)
          acc[m][nt] = __builtin_amdgcn_mfma_f32_16x16x32_f16(af[m][kt], bf, acc[m][nt], 0, 0, 0);
      }
    __syncthreads();
#pragma unroll
    for (int m = 0; m < 2; ++m)
#pragma unroll
      for (int nt = 0; nt < 8; ++nt) {
        int Rb = wv * 32 + m * 16 + q * 4;
        int col = nt * 16 + l15;
#pragma unroll
        for (int r = 0; r < 4; ++r) {
          unsigned short hb = f2h(acc[m][nt][r]);
          Mrow[(Rb + r) * HD + col] = hb;
          Mcol[col * HD + (Rb + r)] = hb;
        }
      }
    __syncthreads();
  }
  for (int j = 0; j < 64; ++j) {
    int id = j * 256 + tid;
    Mf[id] = Mrow[id];
  }
}

// ---------------------------------------------------------------------------
// Chunk pass. One block = (chunk c, 32 batch cols). Per step:
//   out[192,32] = W[192,192] @ [x_t ; h_{t-1}][192,32]   (f16 MFMA, fp32 acc)
// W A-fragments pinned in VGPRs; B-vector in LDS ([n][k], swizzled groups).
// Pass A (WRITE_OUT=false): zero init, writes only final h to u_out.
// Pass C (WRITE_OUT=true):  init from s_buf/init_h, writes known+hidden.
// ---------------------------------------------------------------------------
template <bool WRITE_OUT, bool ZERO_INIT>
__global__ __launch_bounds__(256) void rnn_pass(
    const float* __restrict__ x, const unsigned short* __restrict__ Wf,
    const float* __restrict__ init_h, const float* __restrict__ s_buf,
    float* __restrict__ u_out, float* __restrict__ out_known,
    float* __restrict__ out_hidden) {
  const int c = blockIdx.x / NSP;
  const int col0 = (blockIdx.x % NSP) * BC;
  const int tid = threadIdx.x;
  const int wv = tid >> 6;
  const int ln = tid & 63;
  const int l15 = ln & 15;
  const int q = ln >> 4;

  __shared__ __align__(16) unsigned short Bsh[BC * KT];  // 12 KB

  // W fragments: wave wv owns output rows [48*wv, 48*wv+48)
  half8 afrag[3][6];
#pragma unroll
  for (int m = 0; m < 3; ++m)
#pragma unroll
    for (int kt = 0; kt < 6; ++kt)
      afrag[m][kt] = *reinterpret_cast<const half8*>(
          Wf + (wv * 48 + m * 16 + l15) * KT + kt * 32 + q * 8);

  // stage initial hidden state into LDS (k = 64..191)
  {
    const float* hsrc = nullptr;
    if (!ZERO_INIT) hsrc = (c == 0) ? init_h : (s_buf + (size_t)c * HD * BD);
    int b = tid & 31;
    int r0 = (tid >> 5) * 16;
    float hv[16];
#pragma unroll
    for (int j = 0; j < 16; ++j)
      hv[j] = hsrc ? hsrc[(size_t)(r0 + j) * BD + col0 + b] : 0.f;
#pragma unroll
    for (int hf = 0; hf < 2; ++hf) {
      int o = hf * 8;
      uint4 v;
      v.x = pack2(hv[o + 0], hv[o + 1]);
      v.y = pack2(hv[o + 2], hv[o + 3]);
      v.z = pack2(hv[o + 4], hv[o + 5]);
      v.w = pack2(hv[o + 6], hv[o + 7]);
      int k0 = KD + r0 + o;
      *reinterpret_cast<uint4*>(&Bsh[b * KT + swz(k0 >> 3, b) * 8]) = v;
    }
  }
  // stage x for step 0 (k = 0..63)
  {
    int b = tid & 31;
    int k0 = (tid >> 5) * 8;
    const float* xp = x + (size_t)(c * LS) * KD * BD + col0 + b;
    float xv[8];
#pragma unroll
    for (int j = 0; j < 8; ++j) xv[j] = xp[(size_t)(k0 + j) * BD];
    uint4 v;
    v.x = pack2(xv[0], xv[1]);
    v.y = pack2(xv[2], xv[3]);
    v.z = pack2(xv[4], xv[5]);
    v.w = pack2(xv[6], xv[7]);
    *reinterpret_cast<uint4*>(&Bsh[b * KT + swz(k0 >> 3, b) * 8]) = v;
  }
  __syncthreads();

  for (int i = 0; i < LS; ++i) {
    const int t = c * LS + i;
    // prefetch next x into VGPRs (in flight during MFMA phase)
    float xv[8];
    const int b = tid & 31;
    const int xk0 = (tid >> 5) * 8;
    if (i + 1 < LS) {
      const float* xp = x + (size_t)(t + 1) * KD * BD + col0 + b;
#pragma unroll
      for (int j = 0; j < 8; ++j) xv[j] = xp[(size_t)(xk0 + j) * BD];
    }
    // out = W @ [x_t ; h_{t-1}]
    floatx4 acc[3][2];
#pragma unroll
    for (int m = 0; m < 3; ++m)
#pragma unroll
      for (int nt = 0; nt < 2; ++nt) {
        floatx4 z = {0.f, 0.f, 0.f, 0.f};
        acc[m][nt] = z;
      }
#pragma unroll
    for (int kt = 0; kt < 6; ++kt)
#pragma unroll
      for (int nt = 0; nt < 2; ++nt) {
        int n = nt * 16 + l15;
        half8 bf = *reinterpret_cast<const half8*>(
            &Bsh[n * KT + swz(kt * 4 + q, n) * 8]);
#pragma unroll
        for (int m = 0; m < 3; ++m)
          acc[m][nt] = __builtin_amdgcn_mfma_f32_16x16x32_f16(
              afrag[m][kt], bf, acc[m][nt], 0, 0, 0);
      }
    __syncthreads();  // all B-fragment reads done before h overwrite
    // epilogue: C/D layout row = q*4+r, col = l15
#pragma unroll
    for (int m = 0; m < 3; ++m) {
      int Rb = wv * 48 + m * 16 + q * 4;
#pragma unroll
      for (int nt = 0; nt < 2; ++nt) {
        int col = col0 + nt * 16 + l15;
        if (Rb < KD) {
          if (WRITE_OUT) {
            float* kp = out_known + (size_t)t * KD * BD + (size_t)Rb * BD + col;
#pragma unroll
            for (int r = 0; r < 4; ++r) kp[(size_t)r * BD] = acc[m][nt][r];
          }
        } else {
          int hr = Rb - KD;
          if (WRITE_OUT) {
            float* hp = out_hidden + (size_t)t * HD * BD + (size_t)hr * BD + col;
#pragma unroll
            for (int r = 0; r < 4; ++r) hp[(size_t)r * BD] = acc[m][nt][r];
          }
          if (!WRITE_OUT && i == LS - 1) {
            float* up = u_out + ((size_t)c * HD + hr) * BD + col;
#pragma unroll
            for (int r = 0; r < 4; ++r) up[(size_t)r * BD] = acc[m][nt][r];
          }
          // h writeback to LDS for next step (k index == Rb)
          int n = nt * 16 + l15;
          uint2 pk;
          pk.x = pack2(acc[m][nt][0], acc[m][nt][1]);
          pk.y = pack2(acc[m][nt][2], acc[m][nt][3]);
          *reinterpret_cast<uint2*>(&Bsh[n * KT + swz(Rb >> 3, n) * 8 + (Rb & 7)]) = pk;
        }
      }
    }
    // stage prefetched x_{t+1}
    if (i + 1 < LS) {
      uint4 v;
      v.x = pack2(xv[0], xv[1]);
      v.y = pack2(xv[2], xv[3]);
      v.z = pack2(xv[4], xv[5]);
      v.w = pack2(xv[6], xv[7]);
      *reinterpret_cast<uint4*>(&Bsh[b * KT + swz(xk0 >> 3, b) * 8]) = v;
    }
    __syncthreads();
  }
}

// ---------------------------------------------------------------------------
// combine: s[0] = init; s[c+1] = M s[c] + u[c], write s[1..63]. 4 blocks.
// ---------------------------------------------------------------------------
__global__ __launch_bounds__(256) void combine_kernel(
    const unsigned short* __restrict__ Mf, const float* __restrict__ init_h,
    const float* __restrict__ u_buf, float* __restrict__ s_buf) {
  const int col0 = blockIdx.x * BC;
  const int tid = threadIdx.x;
  const int wv = tid >> 6;
  const int ln = tid & 63;
  const int l15 = ln & 15;
  const int q = ln >> 4;
  __shared__ __align__(16) unsigned short Hsh[BC * HD];  // 8 KB

  half8 af[2][4];
#pragma unroll
  for (int m = 0; m < 2; ++m)
#pragma unroll
    for (int kt = 0; kt < 4; ++kt)
      af[m][kt] = *reinterpret_cast<const half8*>(
          Mf + (wv * 32 + m * 16 + l15) * HD + kt * 32 + q * 8);

  {
    int b = tid & 31;
    int r0 = (tid >> 5) * 16;
    float hv[16];
#pragma unroll
    for (int j = 0; j < 16; ++j)
      hv[j] = init_h[(size_t)(r0 + j) * BD + col0 + b];
#pragma unroll
    for (int hf = 0; hf < 2; ++hf) {
      int o = hf * 8;
      uint4 v;
      v.x = pack2(hv[o + 0], hv[o + 1]);
      v.y = pack2(hv[o + 2], hv[o + 3]);
      v.z = pack2(hv[o + 4], hv[o + 5]);
      v.w = pack2(hv[o + 6], hv[o + 7]);
      *reinterpret_cast<uint4*>(&Hsh[b * HD + swz((r0 + o) >> 3, b) * 8]) = v;
    }
  }
  __syncthreads();

  float ua[2][2][4], ub[2][2][4];
  auto load_u = [&](float(&dst)[2][2][4], int cc) {
    const float* up = u_buf + (size_t)cc * HD * BD;
#pragma unroll
    for (int m = 0; m < 2; ++m) {
      int Rb = wv * 32 + m * 16 + q * 4;
#pragma unroll
      for (int nt = 0; nt < 2; ++nt) {
        int col = col0 + nt * 16 + l15;
#pragma unroll
        for (int r = 0; r < 4; ++r)
          dst[m][nt][r] = up[(size_t)(Rb + r) * BD + col];
      }
    }
  };
  auto stepf = [&](int cc, const float(&uc)[2][2][4]) {
    floatx4 acc[2][2];
#pragma unroll
    for (int m = 0; m < 2; ++m)
#pragma unroll
      for (int nt = 0; nt < 2; ++nt) {
        floatx4 z = {0.f, 0.f, 0.f, 0.f};
        acc[m][nt] = z;
      }
#pragma unroll
    for (int kt = 0; kt < 4; ++kt)
#pragma unroll
      for (int nt = 0; nt < 2; ++nt) {
        int n = nt * 16 + l15;
        half8 bf = *reinterpret_cast<const half8*>(
            &Hsh[n * HD + swz(kt * 4 + q, n) * 8]);
#pragma unroll
        for (int m = 0; m < 2; ++m)
          acc[m][nt] = __builtin_amdgcn_mfma_f32_16x16x32_f16(af[m][kt], bf, acc[m][nt], 0, 0, 0);
      }
    __syncthreads();
#pragma unroll
    for (int m = 0; m < 2; ++m) {
      int Rb = wv * 32 + m * 16 + q * 4;
#pragma unroll
      for (int nt = 0; nt < 2; ++nt) {
        int col = col0 + nt * 16 + l15;
        float s0 = acc[m][nt][0] + uc[m][nt][0];
        float s1 = acc[m][nt][1] + uc[m][nt][1];
        float s2 = acc[m][nt][2] + uc[m][nt][2];
        float s3 = acc[m][nt][3] + uc[m][nt][3];
        float* sp = s_buf + ((size_t)(cc + 1) * HD + Rb) * BD + col;
        sp[0] = s0; sp[BD] = s1; sp[2 * BD] = s2; sp[3 * BD] = s3;
        int n = nt * 16 + l15;
        uint2 pk;
        pk.x = pack2(s0, s1);
        pk.y = pack2(s2, s3);
        *reinterpret_cast<uint2*>(&Hsh[n * HD + swz(Rb >> 3, n) * 8 + (Rb & 7)]) = pk;
      }
    }
    __syncthreads();
  };

  load_u(ua, 0);
  load_u(ub, 1);
  int cc = 0;
  while (cc < CH - 1) {
    stepf(cc, ua);
    if (cc + 2 < CH - 1) load_u(ua, cc + 2);
    ++cc;
    if (cc >= CH - 1) break;
    stepf(cc, ub);
    if (cc + 2 < CH - 1) load_u(ub, cc + 2);
    ++cc;
  }
}

// ---------------------------------------------------------------------------
extern "C" void kernel_launch(void* const* d_in, const int* in_sizes, int n_in,
                              void* d_out, int out_size, void* d_ws, size_t ws_size,
                              hipStream_t stream) {
  const float* x  = (const float*)d_in[0];
  const float* ih = (const float*)d_in[1];
  const float* A1 = (const float*)d_in[2];
  const float* A2 = (const float*)d_in[3];
  const float* A3 = (const float*)d_in[4];
  const float* A4 = (const float*)d_in[5];
  char* ws = (char*)d_ws;
  unsigned short* Wf = (unsigned short*)(ws + W_OFF);
  unsigned short* Mf = (unsigned short*)(ws + M_OFF);
  float* u_buf = (float*)(ws + U_OFF);
  float* s_buf = (float*)(ws + S_OFF);
  float* known = (float*)d_out;
  float* hidden = known + (size_t)T * KD * BD;

  prep_kernel<<<37, 256, 0, stream>>>(A1, A2, A3, A4, Wf, Mf);
  rnn_pass<false, true><<<(CH - 1) * NSP, 256, 0, stream>>>(
      x, Wf, nullptr, nullptr, u_buf, nullptr, nullptr);
  combine_kernel<<<NSP, 256, 0, stream>>>(Mf, ih, u_buf, s_buf);
  rnn_pass<true, false><<<CH * NSP, 256, 0, stream>>>(
      x, Wf, ih, s_buf, nullptr, known, hidden);
}

// Round 2
// 645.357 us; speedup vs baseline: 1.0594x; 1.0594x over previous
//
#include <hip/hip_runtime.h>
#include <stdint.h>

typedef _Float16 half8 __attribute__((ext_vector_type(8)));
typedef float floatx4 __attribute__((ext_vector_type(4)));

constexpr int T  = 4096;
constexpr int KD = 64;    // known dim
constexpr int HD = 128;   // hidden dim
constexpr int BD = 128;   // batch
constexpr int KT = KD + HD;   // 192 = combined W rows / B-vector length
constexpr int CH = 128;       // chunks
constexpr int LS = T / CH;    // 32 steps per chunk
constexpr int BC = 32;        // batch cols per block
constexpr int NSP = BD / BC;  // 4 batch splits
constexpr int G  = 8;         // chunks per combine group
constexpr int NG = CH / G;    // 16 groups

static_assert(CH * LS == T, "");
static_assert(NG * G == CH, "");

// ws layout (bytes)
constexpr size_t W_OFF  = 0;                                   // 192*192 f16 = 73728
constexpr size_t M_OFF  = 73728;                               // A4^LS   f16 [128][128] = 32768
constexpr size_t M8_OFF = M_OFF + 32768;                       // A4^(LS*G) f16 = 32768
constexpr size_t U_OFF  = M8_OFF + 32768;                      // u16 [CH][BD][HD] f16 = 4 MB
constexpr size_t S_OFF  = U_OFF + (size_t)CH * BD * HD * 2;    // s16 [CH][BD][HD] f16 = 4 MB
constexpr size_t AGG_OFF = S_OFF + (size_t)CH * BD * HD * 2;   // agg16 [NG-1][BD][HD] f16

__device__ __forceinline__ unsigned short f2h(float v) {
  _Float16 h = (_Float16)v;
  return __builtin_bit_cast(unsigned short, h);
}
__device__ __forceinline__ float h2f(unsigned short u) {
  return (float)__builtin_bit_cast(_Float16, u);
}
__device__ __forceinline__ unsigned pack2(float a, float b) {
  return (unsigned)f2h(a) | ((unsigned)f2h(b) << 16);
}
// XOR swizzle of 16B groups within aligned 8-group sets: conflict-free b128 reads
__device__ __forceinline__ int swz(int g, int n) {
  return (g & ~7) | ((g & 7) ^ (n & 7));
}

// ---------------------------------------------------------------------------
// prep: W (f16 [192][192]); M = A4^32 (5 squarings); M8 = A4^256 (8 squarings)
// ---------------------------------------------------------------------------
__global__ __launch_bounds__(256) void prep_kernel(
    const float* __restrict__ A1, const float* __restrict__ A2,
    const float* __restrict__ A3, const float* __restrict__ A4,
    unsigned short* __restrict__ Wf, unsigned short* __restrict__ Mf,
    unsigned short* __restrict__ M8f) {
  if (blockIdx.x < 36) {
    for (int e = 0; e < 4; ++e) {
      int id = blockIdx.x * 1024 + e * 256 + threadIdx.x;  // 36*1024 = 36864 = 192*192
      int r = id / KT, cc = id % KT;
      float v;
      if (r < KD) v = (cc < KD) ? A1[r * KD + cc] : A2[r * HD + (cc - KD)];
      else        v = (cc < KD) ? A3[(r - KD) * KD + cc] : A4[(r - KD) * HD + (cc - KD)];
      Wf[id] = f2h(v);
    }
    return;
  }
  // block 36: repeated squaring of A4 in LDS (Mrow row-major, Mcol transposed)
  __shared__ __align__(16) unsigned short Mrow[HD * HD];
  __shared__ __align__(16) unsigned short Mcol[HD * HD];
  const int tid = threadIdx.x;
  for (int j = 0; j < 64; ++j) {
    int id = j * 256 + tid;
    int r = id >> 7, cc = id & 127;
    unsigned short hb = f2h(A4[id]);
    Mrow[id] = hb;
    Mcol[cc * HD + r] = hb;
  }
  __syncthreads();
  const int wv = tid >> 6, ln = tid & 63, l15 = ln & 15, q = ln >> 4;
  for (int it = 0; it < 8; ++it) {
    half8 af[2][4];
#pragma unroll
    for (int m = 0; m < 2; ++m)
#pragma unroll
      for (int kt = 0; kt < 4; ++kt)
        af[m][kt] = *reinterpret_cast<const half8*>(
            &Mrow[(wv * 32 + m * 16 + l15) * HD + kt * 32 + q * 8]);
    floatx4 acc[2][8];
#pragma unroll
    for (int m = 0; m < 2; ++m)
#pragma unroll
      for (int nt = 0; nt < 8; ++nt) {
        floatx4 z = {0.f, 0.f, 0.f, 0.f};
        acc[m][nt] = z;
      }
#pragma unroll
    for (int kt = 0; kt < 4; ++kt)
#pragma unroll
      for (int nt = 0; nt < 8; ++nt) {
        half8 bf = *reinterpret_cast<const half8*>(
            &Mcol[(nt * 16 + l15) * HD + kt * 32 + q * 8]);
#pragma unroll
        for (int m = 0; m < 2; ++m)
          acc[m][nt] = __builtin_amdgcn_mfma_f32_16x16x32_f16(af[m][kt], bf, acc[m][nt], 0, 0, 0);
      }
    __syncthreads();
#pragma unroll
    for (int m = 0; m < 2; ++m)
#pragma unroll
      for (int nt = 0; nt < 8; ++nt) {
        int Rb = wv * 32 + m * 16 + q * 4;
        int col = nt * 16 + l15;
#pragma unroll
        for (int r = 0; r < 4; ++r) {
          unsigned short hb = f2h(acc[m][nt][r]);
          Mrow[(Rb + r) * HD + col] = hb;
          Mcol[col * HD + (Rb + r)] = hb;
        }
      }
    __syncthreads();
    if (it == 4) {  // 5 squarings done: A4^32
      for (int j = 0; j < 64; ++j) {
        int id = j * 256 + tid;
        Mf[id] = Mrow[id];
      }
    }
    if (it == 7) {  // 8 squarings done: A4^256
      for (int j = 0; j < 64; ++j) {
        int id = j * 256 + tid;
        M8f[id] = Mrow[id];
      }
    }
  }
}

// ---------------------------------------------------------------------------
// Chunk pass. One block = (chunk c, 32 batch cols). Per step:
//   out[192,32] = W[192,192] @ [x_t ; h_{t-1}][192,32]   (f16 MFMA, fp32 acc)
// W A-fragments pinned in VGPRs; B-vector in LDS ([n][k], swizzled groups).
// Pass A (WRITE_OUT=false): zero init, writes only final h (f16) to u16.
// Pass C (WRITE_OUT=true):  init from s16/init_h, writes known+hidden.
// ---------------------------------------------------------------------------
template <bool WRITE_OUT, bool ZERO_INIT>
__global__ __launch_bounds__(256, 2) void rnn_pass(
    const float* __restrict__ x, const unsigned short* __restrict__ Wf,
    const float* __restrict__ init_h, const unsigned short* __restrict__ s16,
    unsigned short* __restrict__ u16, float* __restrict__ out_known,
    float* __restrict__ out_hidden) {
  const int c = blockIdx.x / NSP;
  const int col0 = (blockIdx.x % NSP) * BC;
  const int tid = threadIdx.x;
  const int wv = tid >> 6;
  const int ln = tid & 63;
  const int l15 = ln & 15;
  const int q = ln >> 4;

  __shared__ __align__(16) unsigned short Bsh[BC * KT];  // 12 KB

  // W fragments: wave wv owns output rows [48*wv, 48*wv+48)
  half8 afrag[3][6];
#pragma unroll
  for (int m = 0; m < 3; ++m)
#pragma unroll
    for (int kt = 0; kt < 6; ++kt)
      afrag[m][kt] = *reinterpret_cast<const half8*>(
          Wf + (wv * 48 + m * 16 + l15) * KT + kt * 32 + q * 8);

  // stage initial hidden state into LDS (k = 64..191)
  {
    int b = tid & 31;
    int r0 = (tid >> 5) * 16;
    if (ZERO_INIT) {
      uint4 z = {0u, 0u, 0u, 0u};
      *reinterpret_cast<uint4*>(&Bsh[b * KT + swz((KD + r0) >> 3, b) * 8]) = z;
      *reinterpret_cast<uint4*>(&Bsh[b * KT + swz((KD + r0 + 8) >> 3, b) * 8]) = z;
    } else if (c == 0) {
      float hv[16];
#pragma unroll
      for (int j = 0; j < 16; ++j)
        hv[j] = init_h[(size_t)(r0 + j) * BD + col0 + b];
#pragma unroll
      for (int hf = 0; hf < 2; ++hf) {
        int o = hf * 8;
        uint4 v;
        v.x = pack2(hv[o + 0], hv[o + 1]);
        v.y = pack2(hv[o + 2], hv[o + 3]);
        v.z = pack2(hv[o + 4], hv[o + 5]);
        v.w = pack2(hv[o + 6], hv[o + 7]);
        *reinterpret_cast<uint4*>(&Bsh[b * KT + swz((KD + r0 + o) >> 3, b) * 8]) = v;
      }
    } else {
      const unsigned short* sp = s16 + ((size_t)c * BD + col0 + b) * HD + r0;
      uint4 v0 = *reinterpret_cast<const uint4*>(sp);
      uint4 v1 = *reinterpret_cast<const uint4*>(sp + 8);
      *reinterpret_cast<uint4*>(&Bsh[b * KT + swz((KD + r0) >> 3, b) * 8]) = v0;
      *reinterpret_cast<uint4*>(&Bsh[b * KT + swz((KD + r0 + 8) >> 3, b) * 8]) = v1;
    }
  }
  // stage x for step 0 (k = 0..63)
  {
    int b = tid & 31;
    int k0 = (tid >> 5) * 8;
    const float* xp = x + (size_t)(c * LS) * KD * BD + col0 + b;
    float xv[8];
#pragma unroll
    for (int j = 0; j < 8; ++j) xv[j] = xp[(size_t)(k0 + j) * BD];
    uint4 v;
    v.x = pack2(xv[0], xv[1]);
    v.y = pack2(xv[2], xv[3]);
    v.z = pack2(xv[4], xv[5]);
    v.w = pack2(xv[6], xv[7]);
    *reinterpret_cast<uint4*>(&Bsh[b * KT + swz(k0 >> 3, b) * 8]) = v;
  }
  __syncthreads();

  for (int i = 0; i < LS; ++i) {
    const int t = c * LS + i;
    // prefetch next x into VGPRs (in flight during MFMA phase)
    float xv[8];
    const int b = tid & 31;
    const int xk0 = (tid >> 5) * 8;
    if (i + 1 < LS) {
      const float* xp = x + (size_t)(t + 1) * KD * BD + col0 + b;
#pragma unroll
      for (int j = 0; j < 8; ++j) xv[j] = xp[(size_t)(xk0 + j) * BD];
    }
    // out = W @ [x_t ; h_{t-1}]
    floatx4 acc[3][2];
#pragma unroll
    for (int m = 0; m < 3; ++m)
#pragma unroll
      for (int nt = 0; nt < 2; ++nt) {
        floatx4 z = {0.f, 0.f, 0.f, 0.f};
        acc[m][nt] = z;
      }
#pragma unroll
    for (int kt = 0; kt < 6; ++kt)
#pragma unroll
      for (int nt = 0; nt < 2; ++nt) {
        int n = nt * 16 + l15;
        half8 bf = *reinterpret_cast<const half8*>(
            &Bsh[n * KT + swz(kt * 4 + q, n) * 8]);
#pragma unroll
        for (int m = 0; m < 3; ++m)
          acc[m][nt] = __builtin_amdgcn_mfma_f32_16x16x32_f16(
              afrag[m][kt], bf, acc[m][nt], 0, 0, 0);
      }
    __syncthreads();  // all B-fragment reads done before h overwrite
    // epilogue: C/D layout row = q*4+r, col = l15
#pragma unroll
    for (int m = 0; m < 3; ++m) {
      int Rb = wv * 48 + m * 16 + q * 4;
#pragma unroll
      for (int nt = 0; nt < 2; ++nt) {
        int col = col0 + nt * 16 + l15;
        if (Rb < KD) {
          if (WRITE_OUT) {
            float* kp = out_known + (size_t)t * KD * BD + (size_t)Rb * BD + col;
#pragma unroll
            for (int r = 0; r < 4; ++r) kp[(size_t)r * BD] = acc[m][nt][r];
          }
        } else {
          int hr = Rb - KD;
          if (WRITE_OUT) {
            float* hp = out_hidden + (size_t)t * HD * BD + (size_t)hr * BD + col;
#pragma unroll
            for (int r = 0; r < 4; ++r) hp[(size_t)r * BD] = acc[m][nt][r];
          }
          if (!WRITE_OUT && i == LS - 1) {
            // u16 layout [c][b][h]: 4 consecutive h per lane -> one 8B store
            unsigned short* up = u16 + ((size_t)c * BD + col) * HD + hr;
            uint2 pku;
            pku.x = pack2(acc[m][nt][0], acc[m][nt][1]);
            pku.y = pack2(acc[m][nt][2], acc[m][nt][3]);
            *reinterpret_cast<uint2*>(up) = pku;
          }
          // h writeback to LDS for next step (k index == Rb)
          int n = nt * 16 + l15;
          uint2 pk;
          pk.x = pack2(acc[m][nt][0], acc[m][nt][1]);
          pk.y = pack2(acc[m][nt][2], acc[m][nt][3]);
          *reinterpret_cast<uint2*>(&Bsh[n * KT + swz(Rb >> 3, n) * 8 + (Rb & 7)]) = pk;
        }
      }
    }
    // stage prefetched x_{t+1}
    if (i + 1 < LS) {
      uint4 v;
      v.x = pack2(xv[0], xv[1]);
      v.y = pack2(xv[2], xv[3]);
      v.z = pack2(xv[4], xv[5]);
      v.w = pack2(xv[6], xv[7]);
      *reinterpret_cast<uint4*>(&Bsh[b * KT + swz(xk0 >> 3, b) * 8]) = v;
    }
    __syncthreads();
  }
}

// ---------------------------------------------------------------------------
// combine helpers (state in Hsh [BC][HD] swizzled f16; M fragments in VGPRs)
// ---------------------------------------------------------------------------
__device__ __forceinline__ void load_mfrag(const unsigned short* Mp, half8 (&af)[2][4],
                                           int wv, int l15, int q) {
#pragma unroll
  for (int m = 0; m < 2; ++m)
#pragma unroll
    for (int kt = 0; kt < 4; ++kt)
      af[m][kt] = *reinterpret_cast<const half8*>(
          Mp + (wv * 32 + m * 16 + l15) * HD + kt * 32 + q * 8);
}

__device__ __forceinline__ void stage_h_f32(const float* __restrict__ hsrc,
                                            unsigned short* Hsh, int col0, int tid) {
  int b = tid & 31;
  int r0 = (tid >> 5) * 16;
  float hv[16];
#pragma unroll
  for (int j = 0; j < 16; ++j)
    hv[j] = hsrc[(size_t)(r0 + j) * BD + col0 + b];
#pragma unroll
  for (int hf = 0; hf < 2; ++hf) {
    int o = hf * 8;
    uint4 v;
    v.x = pack2(hv[o + 0], hv[o + 1]);
    v.y = pack2(hv[o + 2], hv[o + 3]);
    v.z = pack2(hv[o + 4], hv[o + 5]);
    v.w = pack2(hv[o + 6], hv[o + 7]);
    *reinterpret_cast<uint4*>(&Hsh[b * HD + swz((r0 + o) >> 3, b) * 8]) = v;
  }
}

__device__ __forceinline__ void stage_h_f16(const unsigned short* __restrict__ sp16,
                                            unsigned short* Hsh, int col0, int tid) {
  int b = tid & 31;
  int r0 = (tid >> 5) * 16;
  const unsigned short* sp = sp16 + ((size_t)col0 + b) * HD + r0;
  uint4 v0 = *reinterpret_cast<const uint4*>(sp);
  uint4 v1 = *reinterpret_cast<const uint4*>(sp + 8);
  *reinterpret_cast<uint4*>(&Hsh[b * HD + swz(r0 >> 3, b) * 8]) = v0;
  *reinterpret_cast<uint4*>(&Hsh[b * HD + swz((r0 + 8) >> 3, b) * 8]) = v1;
}

// one combine step: state' = M*state + u ; state in Hsh; u/s in [b][h] f16
template <bool WRITE_S>
__device__ __forceinline__ void comb_step(
    const half8 (&af)[2][4], unsigned short* Hsh,
    const unsigned short* __restrict__ uc, unsigned short* __restrict__ sc,
    int col0, int wv, int l15, int q) {
  floatx4 acc[2][2];
#pragma unroll
  for (int m = 0; m < 2; ++m)
#pragma unroll
    for (int nt = 0; nt < 2; ++nt) {
      floatx4 z = {0.f, 0.f, 0.f, 0.f};
      acc[m][nt] = z;
    }
#pragma unroll
  for (int kt = 0; kt < 4; ++kt)
#pragma unroll
    for (int nt = 0; nt < 2; ++nt) {
      int n = nt * 16 + l15;
      half8 bf = *reinterpret_cast<const half8*>(
          &Hsh[n * HD + swz(kt * 4 + q, n) * 8]);
#pragma unroll
      for (int m = 0; m < 2; ++m)
        acc[m][nt] = __builtin_amdgcn_mfma_f32_16x16x32_f16(af[m][kt], bf, acc[m][nt], 0, 0, 0);
    }
  __syncthreads();
#pragma unroll
  for (int m = 0; m < 2; ++m) {
    int Rb = wv * 32 + m * 16 + q * 4;
#pragma unroll
    for (int nt = 0; nt < 2; ++nt) {
      int col = col0 + nt * 16 + l15;
      uint2 uv = *reinterpret_cast<const uint2*>(uc + (size_t)col * HD + Rb);
      float s0 = acc[m][nt][0] + h2f((unsigned short)(uv.x & 0xffff));
      float s1 = acc[m][nt][1] + h2f((unsigned short)(uv.x >> 16));
      float s2 = acc[m][nt][2] + h2f((unsigned short)(uv.y & 0xffff));
      float s3 = acc[m][nt][3] + h2f((unsigned short)(uv.y >> 16));
      uint2 pk;
      pk.x = pack2(s0, s1);
      pk.y = pack2(s2, s3);
      if (WRITE_S) *reinterpret_cast<uint2*>(sc + (size_t)col * HD + Rb) = pk;
      int n = nt * 16 + l15;
      *reinterpret_cast<uint2*>(&Hsh[n * HD + swz(Rb >> 3, n) * 8 + (Rb & 7)]) = pk;
    }
  }
  __syncthreads();
}

// phase 1: group aggregates a[j] = prefix_{i<G} M^{G-1-i} u[jG+i]; j = 0..NG-2
__global__ __launch_bounds__(256) void combine_agg(
    const unsigned short* __restrict__ Mf, const unsigned short* __restrict__ u16,
    unsigned short* __restrict__ agg16) {
  const int j = blockIdx.x / NSP;
  const int col0 = (blockIdx.x % NSP) * BC;
  const int tid = threadIdx.x;
  const int wv = tid >> 6, ln = tid & 63, l15 = ln & 15, q = ln >> 4;
  __shared__ __align__(16) unsigned short Hsh[BC * HD];
  half8 af[2][4];
  load_mfrag(Mf, af, wv, l15, q);
  for (int jj = tid; jj < BC * HD; jj += 256) Hsh[jj] = 0;
  __syncthreads();
  for (int i = 0; i < G; ++i) {
    const unsigned short* uc = u16 + (size_t)(j * G + i) * BD * HD;
    if (i == G - 1)
      comb_step<true>(af, Hsh, uc, agg16 + (size_t)j * BD * HD, col0, wv, l15, q);
    else
      comb_step<false>(af, Hsh, uc, nullptr, col0, wv, l15, q);
  }
}

// phase 2: serial group scan  s[(j+1)G] = M8 s[jG] + a[j], j = 0..NG-2
__global__ __launch_bounds__(256) void combine_serial(
    const unsigned short* __restrict__ M8f, const float* __restrict__ init_h,
    const unsigned short* __restrict__ agg16, unsigned short* __restrict__ s16) {
  const int col0 = blockIdx.x * BC;
  const int tid = threadIdx.x;
  const int wv = tid >> 6, ln = tid & 63, l15 = ln & 15, q = ln >> 4;
  __shared__ __align__(16) unsigned short Hsh[BC * HD];
  half8 af[2][4];
  load_mfrag(M8f, af, wv, l15, q);
  stage_h_f32(init_h, Hsh, col0, tid);
  __syncthreads();
  for (int j = 0; j < NG - 1; ++j)
    comb_step<true>(af, Hsh, agg16 + (size_t)j * BD * HD,
                    s16 + (size_t)(j + 1) * G * BD * HD, col0, wv, l15, q);
}

// phase 3: fill within groups  s[jG+i+1] = M s[jG+i] + u[jG+i], i = 0..G-2
__global__ __launch_bounds__(256) void combine_fill(
    const unsigned short* __restrict__ Mf, const float* __restrict__ init_h,
    const unsigned short* __restrict__ u16, unsigned short* __restrict__ s16) {
  const int j = blockIdx.x / NSP;
  const int col0 = (blockIdx.x % NSP) * BC;
  const int tid = threadIdx.x;
  const int wv = tid >> 6, ln = tid & 63, l15 = ln & 15, q = ln >> 4;
  __shared__ __align__(16) unsigned short Hsh[BC * HD];
  half8 af[2][4];
  load_mfrag(Mf, af, wv, l15, q);
  if (j == 0) stage_h_f32(init_h, Hsh, col0, tid);
  else        stage_h_f16(s16 + (size_t)j * G * BD * HD, Hsh, col0, tid);
  __syncthreads();
  for (int i = 0; i < G - 1; ++i)
    comb_step<true>(af, Hsh, u16 + (size_t)(j * G + i) * BD * HD,
                    s16 + (size_t)(j * G + i + 1) * BD * HD, col0, wv, l15, q);
}

// ---------------------------------------------------------------------------
extern "C" void kernel_launch(void* const* d_in, const int* in_sizes, int n_in,
                              void* d_out, int out_size, void* d_ws, size_t ws_size,
                              hipStream_t stream) {
  const float* x  = (const float*)d_in[0];
  const float* ih = (const float*)d_in[1];
  const float* A1 = (const float*)d_in[2];
  const float* A2 = (const float*)d_in[3];
  const float* A3 = (const float*)d_in[4];
  const float* A4 = (const float*)d_in[5];
  char* ws = (char*)d_ws;
  unsigned short* Wf  = (unsigned short*)(ws + W_OFF);
  unsigned short* Mf  = (unsigned short*)(ws + M_OFF);
  unsigned short* M8f = (unsigned short*)(ws + M8_OFF);
  unsigned short* u16 = (unsigned short*)(ws + U_OFF);
  unsigned short* s16 = (unsigned short*)(ws + S_OFF);
  unsigned short* agg16 = (unsigned short*)(ws + AGG_OFF);
  float* known = (float*)d_out;
  float* hidden = known + (size_t)T * KD * BD;

  prep_kernel<<<37, 256, 0, stream>>>(A1, A2, A3, A4, Wf, Mf, M8f);
  rnn_pass<false, true><<<(CH - 1) * NSP, 256, 0, stream>>>(
      x, Wf, nullptr, nullptr, u16, nullptr, nullptr);
  combine_agg<<<(NG - 1) * NSP, 256, 0, stream>>>(Mf, u16, agg16);
  combine_serial<<<NSP, 256, 0, stream>>>(M8f, ih, agg16, s16);
  combine_fill<<<NG * NSP, 256, 0, stream>>>(Mf, ih, u16, s16);
  rnn_pass<true, false><<<CH * NSP, 256, 0, stream>>>(
      x, Wf, ih, s16, nullptr, known, hidden);
}